// Round 1
// baseline (1071.699 us; speedup 1.0000x reference)
//
#include <hip/hip_runtime.h>

typedef unsigned int uint;
typedef unsigned short ushort;

#define D 512
#define LBM 128
#define LBN 128
#define LBK 32

typedef __attribute__((ext_vector_type(8))) short bf16x8;
typedef __attribute__((ext_vector_type(4))) float f32x4;

__device__ __forceinline__ ushort f2b(float f) {
  uint u = __builtin_bit_cast(uint, f);
  return (ushort)((u + 0x7FFFu + ((u >> 16) & 1u)) >> 16);  // RNE
}
__device__ __forceinline__ float b_lo(uint u) { return __builtin_bit_cast(float, u << 16); }
__device__ __forceinline__ float b_hi(uint u) { return __builtin_bit_cast(float, u & 0xFFFF0000u); }

__device__ __forceinline__ void gload16(const void* g, void* l) {
  __builtin_amdgcn_global_load_lds((const __attribute__((address_space(1))) void*)g,
                                   (__attribute__((address_space(3))) void*)l, 16, 0, 0);
}

// ---------------- f32 -> bf16 bulk convert (8 elems/thread) ----------------
__global__ __launch_bounds__(256) void f32_to_bf16_vec(const float* __restrict__ in,
                                                       ushort* __restrict__ out, int n8) {
  const int i = blockIdx.x * 256 + threadIdx.x;
  if (i >= n8) return;
  const float4* p = (const float4*)in + (size_t)i * 2;
  float4 a = p[0], b = p[1];
  uint4 o;
  o.x = f2b(a.x) | ((uint)f2b(a.y) << 16);
  o.y = f2b(a.z) | ((uint)f2b(a.w) << 16);
  o.z = f2b(b.x) | ((uint)f2b(b.y) << 16);
  o.w = f2b(b.z) | ((uint)f2b(b.w) << 16);
  ((uint4*)out)[i] = o;
}

// ------------- transpose 512x512 f32 [k][o] -> bf16 BT [o][k] --------------
__global__ __launch_bounds__(256) void transpose_bf16(const float* __restrict__ W,
                                                      ushort* __restrict__ BT) {
  __shared__ float tile[64][65];
  const int bk = blockIdx.x * 64;  // k block
  const int bo = blockIdx.y * 64;  // o block
  const int tx = threadIdx.x & 63, ty = threadIdx.x >> 6;
#pragma unroll
  for (int r = 0; r < 64; r += 4)
    tile[r + ty][tx] = W[(size_t)(bk + r + ty) * D + bo + tx];
  __syncthreads();
#pragma unroll
  for (int r = 0; r < 64; r += 4)
    BT[(size_t)(bo + r + ty) * D + bk + tx] = f2b(tile[tx][r + ty]);
}

// ---------------------------- CSR build ------------------------------------
__global__ void count_deg(const int* __restrict__ dst, int* __restrict__ deg, int E) {
  const int e = blockIdx.x * 256 + threadIdx.x;
  if (e < E) atomicAdd(&deg[dst[e]], 1);
}

__global__ __launch_bounds__(256) void scan_block(const int* __restrict__ in,
                                                  int* __restrict__ out,
                                                  int* __restrict__ bsum) {
  __shared__ int sm[256];
  const int t = threadIdx.x;
  const int gi = blockIdx.x * 256 + t;
  const int v = in[gi];
  int x = v;
  sm[t] = x;
  __syncthreads();
#pragma unroll
  for (int off = 1; off < 256; off <<= 1) {
    const int y = (t >= off) ? sm[t - off] : 0;
    __syncthreads();
    x += y;
    sm[t] = x;
    __syncthreads();
  }
  out[gi] = x - v;  // exclusive
  if (t == 255 && bsum) bsum[blockIdx.x] = x;
}

__global__ void scan_fixup(int* __restrict__ rowptr, const int* __restrict__ bsum,
                           int* __restrict__ cursor, int N, int E) {
  const int i = blockIdx.x * 256 + threadIdx.x;
  const int r = rowptr[i] + bsum[i >> 8];
  rowptr[i] = r;
  cursor[i] = r;
  if (i == 0) rowptr[N] = E;
}

__global__ void fill_csr(const int* __restrict__ src, const int* __restrict__ dst,
                         int* __restrict__ cursor, int* __restrict__ csr, int E) {
  const int e = blockIdx.x * 256 + threadIdx.x;
  if (e >= E) return;
  const int pos = atomicAdd(&cursor[dst[e]], 1);
  csr[pos] = src[e];
}

// ------------------- graph start offsets (batch is sorted) -----------------
__global__ void compute_gstart(const int* __restrict__ batch, int* __restrict__ gstart,
                               int N, int B) {
  const int n = blockIdx.x * 256 + threadIdx.x;
  if (n >= N) return;
  const int b = batch[n];
  const int bp = (n == 0) ? -1 : batch[n - 1];
  for (int x = bp + 1; x <= b; ++x) gstart[x] = n;
  if (n == N - 1)
    for (int x = b + 1; x <= B; ++x) gstart[x] = N;
}

// --------------- GIN aggregation: h = (1+eps)*x + sum_nbr x ----------------
__global__ __launch_bounds__(256) void agg_kernel(const ushort* __restrict__ xb,
                                                  const int* __restrict__ rowptr,
                                                  const int* __restrict__ csr,
                                                  const float* __restrict__ eps_arr,
                                                  int layer, ushort* __restrict__ h) {
  const int node = blockIdx.x * 4 + (threadIdx.x >> 6);
  const int lane = threadIdx.x & 63;
  const float sc = 1.0f + eps_arr[layer];
  const size_t base = (size_t)node * D + lane * 8;
  const uint4 u = *(const uint4*)(xb + base);
  float a[8];
  a[0] = b_lo(u.x) * sc; a[1] = b_hi(u.x) * sc;
  a[2] = b_lo(u.y) * sc; a[3] = b_hi(u.y) * sc;
  a[4] = b_lo(u.z) * sc; a[5] = b_hi(u.z) * sc;
  a[6] = b_lo(u.w) * sc; a[7] = b_hi(u.w) * sc;
  const int en = rowptr[node + 1];
  for (int e = rowptr[node]; e < en; ++e) {
    const int s = csr[e];
    const uint4 v = *(const uint4*)(xb + (size_t)s * D + lane * 8);
    a[0] += b_lo(v.x); a[1] += b_hi(v.x);
    a[2] += b_lo(v.y); a[3] += b_hi(v.y);
    a[4] += b_lo(v.z); a[5] += b_hi(v.z);
    a[6] += b_lo(v.w); a[7] += b_hi(v.w);
  }
  uint4 o;
  o.x = f2b(a[0]) | ((uint)f2b(a[1]) << 16);
  o.y = f2b(a[2]) | ((uint)f2b(a[3]) << 16);
  o.z = f2b(a[4]) | ((uint)f2b(a[5]) << 16);
  o.w = f2b(a[6]) | ((uint)f2b(a[7]) << 16);
  *(uint4*)(h + base) = o;
}

// --------- bf16 GEMM (m97 structure): O = leaky(A @ BT^T + bias) -----------
// A [M][512] bf16 row-major, BT [512][512] bf16 with BT[o][k] = W[k][o].
__global__ __launch_bounds__(256) void gemm_bias_leaky(const ushort* __restrict__ A,
                                                       const ushort* __restrict__ BT,
                                                       const float* __restrict__ bias,
                                                       ushort* __restrict__ Obf,
                                                       float* __restrict__ Of32) {
  __shared__ alignas(16) ushort lA[LBM * LBK];  // 8 KB
  __shared__ alignas(16) ushort lB[LBN * LBK];  // 8 KB
  const int tid = threadIdx.x;
  const int lane = tid & 63;
  const int wave = tid >> 6;
  const int wr = wave >> 1, wc = wave & 1;  // 2x2 waves, 64x64 each
  const size_t m0 = (size_t)blockIdx.x * LBM;
  const int n0 = blockIdx.y * LBN;

  const int srow = lane >> 2;       // row within 16-row staging segment
  const int scol = (lane & 3) * 8;  // ushort offset within row (16B chunk)

  f32x4 acc[4][4] = {};

  for (int kt = 0; kt < D / LBK; ++kt) {
    const int k0 = kt * LBK;
#pragma unroll
    for (int s = 0; s < 2; ++s) {
      const int seg = wave * 2 + s;  // 0..7, 16 rows each
      const int row = seg * 16 + srow;
      gload16(A + (m0 + row) * D + k0 + scol, &lA[seg * 16 * LBK]);
      gload16(BT + (size_t)(n0 + row) * D + k0 + scol, &lB[seg * 16 * LBK]);
    }
    __syncthreads();  // drains vmcnt before barrier
    bf16x8 af[4], bfr[4];
    const int kreg = (lane >> 4) * 8;
    const int rsel = lane & 15;
#pragma unroll
    for (int i = 0; i < 4; ++i)
      af[i] = *(const bf16x8*)&lA[(wr * 64 + i * 16 + rsel) * LBK + kreg];
#pragma unroll
    for (int j = 0; j < 4; ++j)
      bfr[j] = *(const bf16x8*)&lB[(wc * 64 + j * 16 + rsel) * LBK + kreg];
#pragma unroll
    for (int i = 0; i < 4; ++i)
#pragma unroll
      for (int j = 0; j < 4; ++j)
        acc[i][j] = __builtin_amdgcn_mfma_f32_16x16x32_bf16(af[i], bfr[j], acc[i][j], 0, 0, 0);
    __syncthreads();
  }

  // epilogue: C/D layout col=lane&15, row=(lane>>4)*4+reg (m89-verified)
  const int rbase = (lane >> 4) * 4;
  const int csel = lane & 15;
#pragma unroll
  for (int i = 0; i < 4; ++i) {
#pragma unroll
    for (int j = 0; j < 4; ++j) {
      const int col = n0 + wc * 64 + j * 16 + csel;
      const float bv = bias[col];
#pragma unroll
      for (int q = 0; q < 4; ++q) {
        const size_t row = m0 + wr * 64 + i * 16 + rbase + q;
        float v = acc[i][j][q] + bv;
        v = (v > 0.f) ? v : 0.01f * v;
        Obf[row * D + col] = f2b(v);
        if (Of32) Of32[row * D + col] = v;
      }
    }
  }
}

// ------------------------- segment max (pooling) ---------------------------
__global__ __launch_bounds__(256) void segmax_partial(const ushort* __restrict__ xb,
                                                      const int* __restrict__ gstart,
                                                      float* __restrict__ partial) {
  const int g = blockIdx.x, s = blockIdx.y, t = threadIdx.x;
  const int st = gstart[g], en = gstart[g + 1];
  const long long cnt = en - st;
  const int lo = st + (int)((cnt * s) >> 3);
  const int hi = st + (int)((cnt * (s + 1)) >> 3);
  float m0 = -3.4e38f, m1 = -3.4e38f;
  for (int n = lo; n < hi; ++n) {
    const uint u = *(const uint*)(xb + (size_t)n * D + t * 2);
    m0 = fmaxf(m0, b_lo(u));
    m1 = fmaxf(m1, b_hi(u));
  }
  float* p = partial + (size_t)(g * 8 + s) * D + t * 2;
  p[0] = m0;
  p[1] = m1;
}

__global__ void segmax_combine(const float* __restrict__ partial, float* __restrict__ maxval) {
  const int i = blockIdx.x * 256 + threadIdx.x;  // < B*D
  const int g = i >> 9, d0 = i & (D - 1);
  float m = partial[(size_t)(g * 8) * D + d0];
#pragma unroll
  for (int s = 1; s < 8; ++s) m = fmaxf(m, partial[(size_t)(g * 8 + s) * D + d0]);
  maxval[i] = m;
}

// -------- part (+)= maxval @ W + bias  (f32, W is [k][o] row-major) --------
__global__ __launch_bounds__(256) void pool_gemm(const float* __restrict__ maxval,
                                                 const float* __restrict__ Wp,
                                                 const float* __restrict__ bias,
                                                 float* __restrict__ part, int accumulate) {
  const int g = blockIdx.x;
  const int o = blockIdx.y * 256 + threadIdx.x;
  const float* mrow = maxval + (size_t)g * D;
  float acc = bias[o];
#pragma unroll 8
  for (int k = 0; k < D; ++k) acc = fmaf(mrow[k], Wp[(size_t)k * D + o], acc);
  const size_t idx = (size_t)g * D + o;
  part[idx] = accumulate ? part[idx] + acc : acc;
}

// ---------------------------------------------------------------------------
extern "C" void kernel_launch(void* const* d_in, const int* in_sizes, int n_in,
                              void* d_out, int out_size, void* d_ws, size_t ws_size,
                              hipStream_t stream) {
  const float* x = (const float*)d_in[0];
  const int* ei = (const int*)d_in[1];
  const int* batch = (const int*)d_in[2];
  const float* proj_w = (const float*)d_in[3];
  const float* proj_b = (const float*)d_in[4];
  const float* lin1_w = (const float*)d_in[5];
  const float* lin1_b = (const float*)d_in[6];
  const float* lin2_w = (const float*)d_in[7];
  const float* lin2_b = (const float*)d_in[8];
  const float* eps = (const float*)d_in[9];
  const float* pool_w = (const float*)d_in[10];
  const float* pool_b = (const float*)d_in[11];

  const int N = in_sizes[0] / D;  // 65536
  const int E = in_sizes[1] / 2;  // 524288
  const int B = 64;
  const int* src = ei;
  const int* dst = ei + E;

  float* part = (float*)d_out;         // [64][512]
  float* xout = part + (size_t)B * D;  // [N][512]

  // workspace carve (~209 MB)
  char* w = (char*)d_ws;
  ushort* xb = (ushort*)w;   w += (size_t)N * D * 2;
  ushort* hb = (ushort*)w;   w += (size_t)N * D * 2;
  ushort* tb = (ushort*)w;   w += (size_t)N * D * 2;
  ushort* l1bt = (ushort*)w; w += (size_t)3 * D * D * 2;
  ushort* l2bt = (ushort*)w; w += (size_t)3 * D * D * 2;
  int* rowptr = (int*)w;     w += (size_t)(N + 4) * 4;
  int* cursor = (int*)w;     w += (size_t)N * 4;
  int* deg = (int*)w;        w += (size_t)N * 4;
  int* csr = (int*)w;        w += (size_t)E * 4;
  int* bsum = (int*)w;       w += 256 * 4;
  int* gstart = (int*)w;     w += 128 * 4;
  float* partial = (float*)w; w += (size_t)B * 8 * D * 4;
  float* maxval = (float*)w;  w += (size_t)B * D * 4;
  (void)ws_size; (void)n_in; (void)out_size;

  hipMemsetAsync(deg, 0, (size_t)N * 4, stream);
  f32_to_bf16_vec<<<(N * (D / 8) + 255) / 256, 256, 0, stream>>>(x, xb, N * (D / 8));
  for (int l = 0; l < 3; ++l) {
    transpose_bf16<<<dim3(8, 8), 256, 0, stream>>>(lin1_w + (size_t)l * D * D,
                                                   l1bt + (size_t)l * D * D);
    transpose_bf16<<<dim3(8, 8), 256, 0, stream>>>(lin2_w + (size_t)l * D * D,
                                                   l2bt + (size_t)l * D * D);
  }
  count_deg<<<(E + 255) / 256, 256, 0, stream>>>(dst, deg, E);
  scan_block<<<N / 256, 256, 0, stream>>>(deg, rowptr, bsum);
  scan_block<<<1, 256, 0, stream>>>(bsum, bsum, (int*)nullptr);
  scan_fixup<<<N / 256, 256, 0, stream>>>(rowptr, bsum, cursor, N, E);
  fill_csr<<<(E + 255) / 256, 256, 0, stream>>>(src, dst, cursor, csr, E);
  compute_gstart<<<(N + 255) / 256, 256, 0, stream>>>(batch, gstart, N, B);

  // part = segmax(x) @ proj_w + proj_b
  segmax_partial<<<dim3(B, 8), 256, 0, stream>>>(xb, gstart, partial);
  segmax_combine<<<B * D / 256, 256, 0, stream>>>(partial, maxval);
  pool_gemm<<<dim3(B, 2), 256, 0, stream>>>(maxval, proj_w, proj_b, part, 0);

  for (int l = 0; l < 3; ++l) {
    agg_kernel<<<N / 4, 256, 0, stream>>>(xb, rowptr, csr, eps, l, hb);
    gemm_bias_leaky<<<dim3(N / LBM, D / LBN), 256, 0, stream>>>(
        hb, l1bt + (size_t)l * D * D, lin1_b + (size_t)l * D, tb, nullptr);
    gemm_bias_leaky<<<dim3(N / LBM, D / LBN), 256, 0, stream>>>(
        tb, l2bt + (size_t)l * D * D, lin2_b + (size_t)l * D, xb,
        (l == 2) ? xout : nullptr);
    segmax_partial<<<dim3(B, 8), 256, 0, stream>>>(xb, gstart, partial);
    segmax_combine<<<B * D / 256, 256, 0, stream>>>(partial, maxval);
    pool_gemm<<<dim3(B, 2), 256, 0, stream>>>(maxval, pool_w + (size_t)l * D * D,
                                              pool_b + (size_t)l * D, part, 1);
  }
}

// Round 2
// 1003.373 us; speedup vs baseline: 1.0681x; 1.0681x over previous
//
#include <hip/hip_runtime.h>

typedef unsigned int uint;
typedef unsigned short ushort;

#define D 512
#define LBM 128
#define LBN 128
#define LBK 32

typedef __attribute__((ext_vector_type(8))) short bf16x8;
typedef __attribute__((ext_vector_type(4))) float f32x4;

__device__ __forceinline__ ushort f2b(float f) {
  uint u = __builtin_bit_cast(uint, f);
  return (ushort)((u + 0x7FFFu + ((u >> 16) & 1u)) >> 16);  // RNE
}
__device__ __forceinline__ float b_lo(uint u) { return __builtin_bit_cast(float, u << 16); }
__device__ __forceinline__ float b_hi(uint u) { return __builtin_bit_cast(float, u & 0xFFFF0000u); }

__device__ __forceinline__ void gload16(const void* g, void* l) {
  __builtin_amdgcn_global_load_lds((const __attribute__((address_space(1))) void*)g,
                                   (__attribute__((address_space(3))) void*)l, 16, 0, 0);
}

// ---------------- f32 -> bf16 bulk convert (8 elems/thread) ----------------
__global__ __launch_bounds__(256) void f32_to_bf16_vec(const float* __restrict__ in,
                                                       ushort* __restrict__ out, int n8) {
  const int i = blockIdx.x * 256 + threadIdx.x;
  if (i >= n8) return;
  const float4* p = (const float4*)in + (size_t)i * 2;
  float4 a = p[0], b = p[1];
  uint4 o;
  o.x = f2b(a.x) | ((uint)f2b(a.y) << 16);
  o.y = f2b(a.z) | ((uint)f2b(a.w) << 16);
  o.z = f2b(b.x) | ((uint)f2b(b.y) << 16);
  o.w = f2b(b.z) | ((uint)f2b(b.w) << 16);
  ((uint4*)out)[i] = o;
}

// ------------- transpose 512x512 f32 [k][o] -> bf16 BT [o][k] --------------
__global__ __launch_bounds__(256) void transpose_bf16(const float* __restrict__ W,
                                                      ushort* __restrict__ BT) {
  __shared__ float tile[64][65];
  const int bk = blockIdx.x * 64;  // k block
  const int bo = blockIdx.y * 64;  // o block
  const int tx = threadIdx.x & 63, ty = threadIdx.x >> 6;
#pragma unroll
  for (int r = 0; r < 64; r += 4)
    tile[r + ty][tx] = W[(size_t)(bk + r + ty) * D + bo + tx];
  __syncthreads();
#pragma unroll
  for (int r = 0; r < 64; r += 4)
    BT[(size_t)(bo + r + ty) * D + bk + tx] = f2b(tile[tx][r + ty]);
}

// ---------------------------- CSR build ------------------------------------
__global__ void count_deg(const int* __restrict__ dst, int* __restrict__ deg, int E) {
  const int e = blockIdx.x * 256 + threadIdx.x;
  if (e < E) atomicAdd(&deg[dst[e]], 1);
}

__global__ __launch_bounds__(256) void scan_block(const int* __restrict__ in,
                                                  int* __restrict__ out,
                                                  int* __restrict__ bsum) {
  __shared__ int sm[256];
  const int t = threadIdx.x;
  const int gi = blockIdx.x * 256 + t;
  const int v = in[gi];
  int x = v;
  sm[t] = x;
  __syncthreads();
#pragma unroll
  for (int off = 1; off < 256; off <<= 1) {
    const int y = (t >= off) ? sm[t - off] : 0;
    __syncthreads();
    x += y;
    sm[t] = x;
    __syncthreads();
  }
  out[gi] = x - v;  // exclusive
  if (t == 255 && bsum) bsum[blockIdx.x] = x;
}

__global__ void scan_fixup(int* __restrict__ rowptr, const int* __restrict__ bsum,
                           int* __restrict__ cursor, int N, int E) {
  const int i = blockIdx.x * 256 + threadIdx.x;
  const int r = rowptr[i] + bsum[i >> 8];
  rowptr[i] = r;
  cursor[i] = r;
  if (i == 0) rowptr[N] = E;
}

__global__ void fill_csr(const int* __restrict__ src, const int* __restrict__ dst,
                         int* __restrict__ cursor, int* __restrict__ csr, int E) {
  const int e = blockIdx.x * 256 + threadIdx.x;
  if (e >= E) return;
  const int pos = atomicAdd(&cursor[dst[e]], 1);
  csr[pos] = src[e];
}

// ------------------- graph start offsets (batch is sorted) -----------------
__global__ void compute_gstart(const int* __restrict__ batch, int* __restrict__ gstart,
                               int N, int B) {
  const int n = blockIdx.x * 256 + threadIdx.x;
  if (n >= N) return;
  const int b = batch[n];
  const int bp = (n == 0) ? -1 : batch[n - 1];
  for (int x = bp + 1; x <= b; ++x) gstart[x] = n;
  if (n == N - 1)
    for (int x = b + 1; x <= B; ++x) gstart[x] = N;
}

// --------------- GIN aggregation: h = (1+eps)*x + sum_nbr x ----------------
__global__ __launch_bounds__(256) void agg_kernel(const ushort* __restrict__ xb,
                                                  const int* __restrict__ rowptr,
                                                  const int* __restrict__ csr,
                                                  const float* __restrict__ eps_arr,
                                                  int layer, ushort* __restrict__ h) {
  const int node = blockIdx.x * 4 + (threadIdx.x >> 6);
  const int lane = threadIdx.x & 63;
  const float sc = 1.0f + eps_arr[layer];
  const size_t base = (size_t)node * D + lane * 8;
  const uint4 u = *(const uint4*)(xb + base);
  float a[8];
  a[0] = b_lo(u.x) * sc; a[1] = b_hi(u.x) * sc;
  a[2] = b_lo(u.y) * sc; a[3] = b_hi(u.y) * sc;
  a[4] = b_lo(u.z) * sc; a[5] = b_hi(u.z) * sc;
  a[6] = b_lo(u.w) * sc; a[7] = b_hi(u.w) * sc;
  const int en = rowptr[node + 1];
  for (int e = rowptr[node]; e < en; ++e) {
    const int s = csr[e];
    const uint4 v = *(const uint4*)(xb + (size_t)s * D + lane * 8);
    a[0] += b_lo(v.x); a[1] += b_hi(v.x);
    a[2] += b_lo(v.y); a[3] += b_hi(v.y);
    a[4] += b_lo(v.z); a[5] += b_hi(v.z);
    a[6] += b_lo(v.w); a[7] += b_hi(v.w);
  }
  uint4 o;
  o.x = f2b(a[0]) | ((uint)f2b(a[1]) << 16);
  o.y = f2b(a[2]) | ((uint)f2b(a[3]) << 16);
  o.z = f2b(a[4]) | ((uint)f2b(a[5]) << 16);
  o.w = f2b(a[6]) | ((uint)f2b(a[7]) << 16);
  *(uint4*)(h + base) = o;
}

// --------- bf16 GEMM (m97 structure): O = leaky(A @ BT^T + bias) -----------
// A [M][512] bf16 row-major, BT [512][512] bf16 with BT[o][k] = W[k][o].
// Grid: x = col-blocks (4), y = row-blocks (512); XCD-chunk swizzled.
// Epilogue: stage C in LDS (union with lA/lB), store full 256B row-chunks.
__global__ __launch_bounds__(256) void gemm_bias_leaky(const ushort* __restrict__ A,
                                                       const ushort* __restrict__ BT,
                                                       const float* __restrict__ bias,
                                                       ushort* __restrict__ Obf,
                                                       float* __restrict__ Of32) {
  __shared__ alignas(16) ushort smem[LBM * LBN];  // 32 KB; loop uses first 16 KB
  ushort* lA = smem;              // [128][32]
  ushort* lB = smem + LBM * LBK;  // [128][32]

  const int tid = threadIdx.x;
  const int lane = tid & 63;
  const int wave = tid >> 6;
  const int wr = wave >> 1, wc = wave & 1;  // 2x2 waves, 64x64 each

  // XCD swizzle: give each XCD a contiguous chunk, col-fastest inside,
  // so the 4 col-blocks sharing an A-tile run on one XCD's L2.
  const int lin = blockIdx.y * gridDim.x + blockIdx.x;  // [0, 2048)
  const int nwg = gridDim.x * gridDim.y;
  const int wg = (lin & 7) * (nwg >> 3) + (lin >> 3);
  const int n0 = (wg & 3) * LBN;
  const size_t m0 = (size_t)(wg >> 2) * LBM;

  const int srow = lane >> 2;       // row within 16-row staging segment
  const int scol = (lane & 3) * 8;  // ushort offset within row (16B chunk)

  f32x4 acc[4][4] = {};

  for (int kt = 0; kt < D / LBK; ++kt) {
    const int k0 = kt * LBK;
#pragma unroll
    for (int s = 0; s < 2; ++s) {
      const int seg = wave * 2 + s;  // 0..7, 16 rows each
      const int row = seg * 16 + srow;
      gload16(A + (m0 + row) * D + k0 + scol, &lA[seg * 16 * LBK]);
      gload16(BT + (size_t)(n0 + row) * D + k0 + scol, &lB[seg * 16 * LBK]);
    }
    __syncthreads();  // drains vmcnt before barrier
    bf16x8 af[4], bfr[4];
    const int kreg = (lane >> 4) * 8;
    const int rsel = lane & 15;
#pragma unroll
    for (int i = 0; i < 4; ++i)
      af[i] = *(const bf16x8*)&lA[(wr * 64 + i * 16 + rsel) * LBK + kreg];
#pragma unroll
    for (int j = 0; j < 4; ++j)
      bfr[j] = *(const bf16x8*)&lB[(wc * 64 + j * 16 + rsel) * LBK + kreg];
#pragma unroll
    for (int i = 0; i < 4; ++i)
#pragma unroll
      for (int j = 0; j < 4; ++j)
        acc[i][j] = __builtin_amdgcn_mfma_f32_16x16x32_bf16(af[i], bfr[j], acc[i][j], 0, 0, 0);
    __syncthreads();
  }

  // ---- epilogue: bias + leaky into LDS tile [128][128] bf16 ----
  // C/D layout: col=lane&15, row=(lane>>4)*4+reg (m89-verified)
  const int rbase = (lane >> 4) * 4;
  const int csel = lane & 15;
#pragma unroll
  for (int i = 0; i < 4; ++i) {
#pragma unroll
    for (int j = 0; j < 4; ++j) {
      const int col = wc * 64 + j * 16 + csel;
      const float bv = bias[n0 + col];
#pragma unroll
      for (int q = 0; q < 4; ++q) {
        const int row = wr * 64 + i * 16 + rbase + q;
        float v = acc[i][j][q] + bv;
        v = (v > 0.f) ? v : 0.01f * v;
        smem[row * LBN + col] = f2b(v);
      }
    }
  }
  __syncthreads();

  // ---- coalesced store: 16 lanes x 16B = 256B contiguous per row ----
  const int chunk = tid & 15;  // 16B chunk within the 128-col slab
#pragma unroll
  for (int it = 0; it < 8; ++it) {
    const int row = it * 16 + (tid >> 4);
    const uint4 vv = *(const uint4*)&smem[row * LBN + chunk * 8];
    *(uint4*)(Obf + (m0 + row) * D + n0 + chunk * 8) = vv;
    if (Of32) {
      float4 f0, f1;
      f0.x = b_lo(vv.x); f0.y = b_hi(vv.x); f0.z = b_lo(vv.y); f0.w = b_hi(vv.y);
      f1.x = b_lo(vv.z); f1.y = b_hi(vv.z); f1.z = b_lo(vv.w); f1.w = b_hi(vv.w);
      float* op = Of32 + (m0 + row) * D + n0 + chunk * 8;
      *(float4*)op = f0;
      *(float4*)(op + 4) = f1;
    }
  }
}

// ------------------------- segment max (pooling) ---------------------------
__global__ __launch_bounds__(256) void segmax_partial(const ushort* __restrict__ xb,
                                                      const int* __restrict__ gstart,
                                                      float* __restrict__ partial) {
  const int g = blockIdx.x, s = blockIdx.y, t = threadIdx.x;
  const int st = gstart[g], en = gstart[g + 1];
  const long long cnt = en - st;
  const int lo = st + (int)((cnt * s) >> 3);
  const int hi = st + (int)((cnt * (s + 1)) >> 3);
  float m0 = -3.4e38f, m1 = -3.4e38f;
  for (int n = lo; n < hi; ++n) {
    const uint u = *(const uint*)(xb + (size_t)n * D + t * 2);
    m0 = fmaxf(m0, b_lo(u));
    m1 = fmaxf(m1, b_hi(u));
  }
  float* p = partial + (size_t)(g * 8 + s) * D + t * 2;
  p[0] = m0;
  p[1] = m1;
}

__global__ void segmax_combine(const float* __restrict__ partial, float* __restrict__ maxval) {
  const int i = blockIdx.x * 256 + threadIdx.x;  // < B*D
  const int g = i >> 9, d0 = i & (D - 1);
  float m = partial[(size_t)(g * 8) * D + d0];
#pragma unroll
  for (int s = 1; s < 8; ++s) m = fmaxf(m, partial[(size_t)(g * 8 + s) * D + d0]);
  maxval[i] = m;
}

// -------- part (+)= maxval @ W + bias  (f32, W is [k][o] row-major) --------
__global__ __launch_bounds__(256) void pool_gemm(const float* __restrict__ maxval,
                                                 const float* __restrict__ Wp,
                                                 const float* __restrict__ bias,
                                                 float* __restrict__ part, int accumulate) {
  const int g = blockIdx.x;
  const int o = blockIdx.y * 256 + threadIdx.x;
  const float* mrow = maxval + (size_t)g * D;
  float acc = bias[o];
#pragma unroll 8
  for (int k = 0; k < D; ++k) acc = fmaf(mrow[k], Wp[(size_t)k * D + o], acc);
  const size_t idx = (size_t)g * D + o;
  part[idx] = accumulate ? part[idx] + acc : acc;
}

// ---------------------------------------------------------------------------
extern "C" void kernel_launch(void* const* d_in, const int* in_sizes, int n_in,
                              void* d_out, int out_size, void* d_ws, size_t ws_size,
                              hipStream_t stream) {
  const float* x = (const float*)d_in[0];
  const int* ei = (const int*)d_in[1];
  const int* batch = (const int*)d_in[2];
  const float* proj_w = (const float*)d_in[3];
  const float* proj_b = (const float*)d_in[4];
  const float* lin1_w = (const float*)d_in[5];
  const float* lin1_b = (const float*)d_in[6];
  const float* lin2_w = (const float*)d_in[7];
  const float* lin2_b = (const float*)d_in[8];
  const float* eps = (const float*)d_in[9];
  const float* pool_w = (const float*)d_in[10];
  const float* pool_b = (const float*)d_in[11];

  const int N = in_sizes[0] / D;  // 65536
  const int E = in_sizes[1] / 2;  // 524288
  const int B = 64;
  const int* src = ei;
  const int* dst = ei + E;

  float* part = (float*)d_out;         // [64][512]
  float* xout = part + (size_t)B * D;  // [N][512]

  // workspace carve (~209 MB)
  char* w = (char*)d_ws;
  ushort* xb = (ushort*)w;   w += (size_t)N * D * 2;
  ushort* hb = (ushort*)w;   w += (size_t)N * D * 2;
  ushort* tb = (ushort*)w;   w += (size_t)N * D * 2;
  ushort* l1bt = (ushort*)w; w += (size_t)3 * D * D * 2;
  ushort* l2bt = (ushort*)w; w += (size_t)3 * D * D * 2;
  int* rowptr = (int*)w;     w += (size_t)(N + 4) * 4;
  int* cursor = (int*)w;     w += (size_t)N * 4;
  int* deg = (int*)w;        w += (size_t)N * 4;
  int* csr = (int*)w;        w += (size_t)E * 4;
  int* bsum = (int*)w;       w += 256 * 4;
  int* gstart = (int*)w;     w += 128 * 4;
  float* partial = (float*)w; w += (size_t)B * 8 * D * 4;
  float* maxval = (float*)w;  w += (size_t)B * D * 4;
  (void)ws_size; (void)n_in; (void)out_size;

  hipMemsetAsync(deg, 0, (size_t)N * 4, stream);
  f32_to_bf16_vec<<<(N * (D / 8) + 255) / 256, 256, 0, stream>>>(x, xb, N * (D / 8));
  for (int l = 0; l < 3; ++l) {
    transpose_bf16<<<dim3(8, 8), 256, 0, stream>>>(lin1_w + (size_t)l * D * D,
                                                   l1bt + (size_t)l * D * D);
    transpose_bf16<<<dim3(8, 8), 256, 0, stream>>>(lin2_w + (size_t)l * D * D,
                                                   l2bt + (size_t)l * D * D);
  }
  count_deg<<<(E + 255) / 256, 256, 0, stream>>>(dst, deg, E);
  scan_block<<<N / 256, 256, 0, stream>>>(deg, rowptr, bsum);
  scan_block<<<1, 256, 0, stream>>>(bsum, bsum, (int*)nullptr);
  scan_fixup<<<N / 256, 256, 0, stream>>>(rowptr, bsum, cursor, N, E);
  fill_csr<<<(E + 255) / 256, 256, 0, stream>>>(src, dst, cursor, csr, E);
  compute_gstart<<<(N + 255) / 256, 256, 0, stream>>>(batch, gstart, N, B);

  // part = segmax(x) @ proj_w + proj_b
  segmax_partial<<<dim3(B, 8), 256, 0, stream>>>(xb, gstart, partial);
  segmax_combine<<<B * D / 256, 256, 0, stream>>>(partial, maxval);
  pool_gemm<<<dim3(B, 2), 256, 0, stream>>>(maxval, proj_w, proj_b, part, 0);

  for (int l = 0; l < 3; ++l) {
    agg_kernel<<<N / 4, 256, 0, stream>>>(xb, rowptr, csr, eps, l, hb);
    gemm_bias_leaky<<<dim3(D / LBN, N / LBM), 256, 0, stream>>>(
        hb, l1bt + (size_t)l * D * D, lin1_b + (size_t)l * D, tb, nullptr);
    gemm_bias_leaky<<<dim3(D / LBN, N / LBM), 256, 0, stream>>>(
        tb, l2bt + (size_t)l * D * D, lin2_b + (size_t)l * D, xb,
        (l == 2) ? xout : nullptr);
    segmax_partial<<<dim3(B, 8), 256, 0, stream>>>(xb, gstart, partial);
    segmax_combine<<<B * D / 256, 256, 0, stream>>>(partial, maxval);
    pool_gemm<<<dim3(B, 2), 256, 0, stream>>>(maxval, pool_w + (size_t)l * D * D,
                                              pool_b + (size_t)l * D, part, 1);
  }
}

// Round 4
// 996.519 us; speedup vs baseline: 1.0754x; 1.0069x over previous
//
#include <hip/hip_runtime.h>

typedef unsigned int uint;
typedef unsigned short ushort;

#define D 512
#define LBM 128
#define LBN 128
#define LBK 32

typedef __attribute__((ext_vector_type(8))) short bf16x8;
typedef __attribute__((ext_vector_type(4))) float f32x4;

__device__ __forceinline__ ushort f2b(float f) {
  uint u = __builtin_bit_cast(uint, f);
  return (ushort)((u + 0x7FFFu + ((u >> 16) & 1u)) >> 16);  // RNE
}
__device__ __forceinline__ float b_lo(uint u) { return __builtin_bit_cast(float, u << 16); }
__device__ __forceinline__ float b_hi(uint u) { return __builtin_bit_cast(float, u & 0xFFFF0000u); }

__device__ __forceinline__ void gload16(const void* g, void* l) {
  __builtin_amdgcn_global_load_lds((const __attribute__((address_space(1))) void*)g,
                                   (__attribute__((address_space(3))) void*)l, 16, 0, 0);
}

// ---------------- f32 -> bf16 bulk convert (8 elems/thread) ----------------
__global__ __launch_bounds__(256) void f32_to_bf16_vec(const float* __restrict__ in,
                                                       ushort* __restrict__ out, int n8) {
  const int i = blockIdx.x * 256 + threadIdx.x;
  if (i >= n8) return;
  const float4* p = (const float4*)in + (size_t)i * 2;
  float4 a = p[0], b = p[1];
  uint4 o;
  o.x = f2b(a.x) | ((uint)f2b(a.y) << 16);
  o.y = f2b(a.z) | ((uint)f2b(a.w) << 16);
  o.z = f2b(b.x) | ((uint)f2b(b.y) << 16);
  o.w = f2b(b.z) | ((uint)f2b(b.w) << 16);
  ((uint4*)out)[i] = o;
}

// ------------- transpose 512x512 f32 [k][o] -> bf16 BT [o][k] --------------
__global__ __launch_bounds__(256) void transpose_bf16(const float* __restrict__ W,
                                                      ushort* __restrict__ BT) {
  __shared__ float tile[64][65];
  const int bk = blockIdx.x * 64;  // k block
  const int bo = blockIdx.y * 64;  // o block
  const int tx = threadIdx.x & 63, ty = threadIdx.x >> 6;
#pragma unroll
  for (int r = 0; r < 64; r += 4)
    tile[r + ty][tx] = W[(size_t)(bk + r + ty) * D + bo + tx];
  __syncthreads();
#pragma unroll
  for (int r = 0; r < 64; r += 4)
    BT[(size_t)(bo + r + ty) * D + bk + tx] = f2b(tile[tx][r + ty]);
}

// ---------------------------- CSR build ------------------------------------
__global__ void count_deg(const int* __restrict__ dst, int* __restrict__ deg, int E) {
  const int e = blockIdx.x * 256 + threadIdx.x;
  if (e < E) atomicAdd(&deg[dst[e]], 1);
}

__global__ __launch_bounds__(256) void scan_block(const int* __restrict__ in,
                                                  int* __restrict__ out,
                                                  int* __restrict__ bsum) {
  __shared__ int sm[256];
  const int t = threadIdx.x;
  const int gi = blockIdx.x * 256 + t;
  const int v = in[gi];
  int x = v;
  sm[t] = x;
  __syncthreads();
#pragma unroll
  for (int off = 1; off < 256; off <<= 1) {
    const int y = (t >= off) ? sm[t - off] : 0;
    __syncthreads();
    x += y;
    sm[t] = x;
    __syncthreads();
  }
  out[gi] = x - v;  // exclusive
  if (t == 255 && bsum) bsum[blockIdx.x] = x;
}

__global__ void scan_fixup(int* __restrict__ rowptr, const int* __restrict__ bsum,
                           int* __restrict__ cursor, int N, int E) {
  const int i = blockIdx.x * 256 + threadIdx.x;
  const int r = rowptr[i] + bsum[i >> 8];
  rowptr[i] = r;
  cursor[i] = r;
  if (i == 0) rowptr[N] = E;
}

__global__ void fill_csr(const int* __restrict__ src, const int* __restrict__ dst,
                         int* __restrict__ cursor, int* __restrict__ csr, int E) {
  const int e = blockIdx.x * 256 + threadIdx.x;
  if (e >= E) return;
  const int pos = atomicAdd(&cursor[dst[e]], 1);
  csr[pos] = src[e];
}

// ------------------- graph start offsets (batch is sorted) -----------------
__global__ void compute_gstart(const int* __restrict__ batch, int* __restrict__ gstart,
                               int N, int B) {
  const int n = blockIdx.x * 256 + threadIdx.x;
  if (n >= N) return;
  const int b = batch[n];
  const int bp = (n == 0) ? -1 : batch[n - 1];
  for (int x = bp + 1; x <= b; ++x) gstart[x] = n;
  if (n == N - 1)
    for (int x = b + 1; x <= B; ++x) gstart[x] = N;
}

// --------------- GIN aggregation: h = (1+eps)*x + sum_nbr x ----------------
// One wave per node; 4-wide unrolled gather to keep 4 x 1KB row loads in
// flight per wave (R2 showed VGPR=12, fully serialized loop -> latency-bound).
#define ACC8(v)                                          \
  a[0] += b_lo((v).x); a[1] += b_hi((v).x);              \
  a[2] += b_lo((v).y); a[3] += b_hi((v).y);              \
  a[4] += b_lo((v).z); a[5] += b_hi((v).z);              \
  a[6] += b_lo((v).w); a[7] += b_hi((v).w)

__global__ __launch_bounds__(256) void agg_kernel(const ushort* __restrict__ xb,
                                                  const int* __restrict__ rowptr,
                                                  const int* __restrict__ csr,
                                                  const float* __restrict__ eps_arr,
                                                  int layer, ushort* __restrict__ h) {
  const int node = blockIdx.x * 4 + (threadIdx.x >> 6);
  const int lane = threadIdx.x & 63;
  const float sc = 1.0f + eps_arr[layer];
  const size_t off = (size_t)lane * 8;
  const size_t base = (size_t)node * D + off;
  const uint4 u = *(const uint4*)(xb + base);
  float a[8];
  a[0] = b_lo(u.x) * sc; a[1] = b_hi(u.x) * sc;
  a[2] = b_lo(u.y) * sc; a[3] = b_hi(u.y) * sc;
  a[4] = b_lo(u.z) * sc; a[5] = b_hi(u.z) * sc;
  a[6] = b_lo(u.w) * sc; a[7] = b_hi(u.w) * sc;
  int e = rowptr[node];
  const int en = rowptr[node + 1];
  for (; e + 4 <= en; e += 4) {
    const int s0 = csr[e], s1 = csr[e + 1], s2 = csr[e + 2], s3 = csr[e + 3];
    const uint4 v0 = *(const uint4*)(xb + (size_t)s0 * D + off);
    const uint4 v1 = *(const uint4*)(xb + (size_t)s1 * D + off);
    const uint4 v2 = *(const uint4*)(xb + (size_t)s2 * D + off);
    const uint4 v3 = *(const uint4*)(xb + (size_t)s3 * D + off);
    ACC8(v0); ACC8(v1); ACC8(v2); ACC8(v3);
  }
  if (e + 2 <= en) {
    const int s0 = csr[e], s1 = csr[e + 1];
    const uint4 v0 = *(const uint4*)(xb + (size_t)s0 * D + off);
    const uint4 v1 = *(const uint4*)(xb + (size_t)s1 * D + off);
    ACC8(v0); ACC8(v1);
    e += 2;
  }
  if (e < en) {
    const int s0 = csr[e];
    const uint4 v0 = *(const uint4*)(xb + (size_t)s0 * D + off);
    ACC8(v0);
  }
  uint4 o;
  o.x = f2b(a[0]) | ((uint)f2b(a[1]) << 16);
  o.y = f2b(a[2]) | ((uint)f2b(a[3]) << 16);
  o.z = f2b(a[4]) | ((uint)f2b(a[5]) << 16);
  o.w = f2b(a[6]) | ((uint)f2b(a[7]) << 16);
  *(uint4*)(h + base) = o;
}

// --------- bf16 GEMM (m97 structure): O = leaky(A @ BT^T + bias) -----------
// A [M][512] bf16 row-major, BT [512][512] bf16 with BT[o][k] = W[k][o].
// LDS tiles chunk-XOR-swizzled (rule 21: permute the GLOBAL source chunk for
// global_load_lds, apply the same XOR on the ds_read chunk):
//   LDS[row][chunk] holds global chunk  chunk ^ ((row>>1)&3).
// Per-16-lane phase every bank is then touched exactly 2x (free), vs 8-way
// before (R1 measured 4.19M SQ_LDS_BANK_CONFLICT per dispatch).
__global__ __launch_bounds__(256) void gemm_bias_leaky(const ushort* __restrict__ A,
                                                       const ushort* __restrict__ BT,
                                                       const float* __restrict__ bias,
                                                       ushort* __restrict__ Obf,
                                                       float* __restrict__ Of32) {
  __shared__ alignas(16) ushort smem[LBM * LBN];  // 32 KB; loop uses first 16 KB
  ushort* lA = smem;              // [128 rows][4 chunks of 8] swizzled
  ushort* lB = smem + LBM * LBK;

  const int tid = threadIdx.x;
  const int lane = tid & 63;
  const int wave = tid >> 6;
  const int wr = wave >> 1, wc = wave & 1;  // 2x2 waves, 64x64 each

  // XCD swizzle: contiguous chunk per XCD, col-fastest inside.
  const int lin = blockIdx.y * gridDim.x + blockIdx.x;
  const int nwg = gridDim.x * gridDim.y;
  const int wg = (lin & 7) * (nwg >> 3) + (lin >> 3);
  const int n0 = (wg & 3) * LBN;
  const size_t m0 = (size_t)(wg >> 2) * LBM;

  const int srow = lane >> 2;  // row within 16-row staging segment
  // global source chunk permuted so the linear LDS dest ends up swizzled:
  const int scol = ((lane & 3) ^ ((lane >> 3) & 3)) * 8;

  f32x4 acc[4][4] = {};

  // fragment-read addressing (swizzled chunk)
  const int rsel = lane & 15;
  const int ksw = (rsel >> 1) & 3;
  const int chunkO = ((lane >> 4) ^ ksw) * 8;  // ushort offset within row

  for (int kt = 0; kt < D / LBK; ++kt) {
    const int k0 = kt * LBK;
#pragma unroll
    for (int s = 0; s < 2; ++s) {
      const int seg = wave * 2 + s;  // 0..7, 16 rows each
      const int row = seg * 16 + srow;
      gload16(A + (m0 + row) * D + k0 + scol, &lA[seg * 16 * LBK]);
      gload16(BT + (size_t)(n0 + row) * D + k0 + scol, &lB[seg * 16 * LBK]);
    }
    __syncthreads();  // drains vmcnt before barrier
    bf16x8 af[4], bfr[4];
#pragma unroll
    for (int i = 0; i < 4; ++i)
      af[i] = *(const bf16x8*)&lA[(wr * 64 + i * 16 + rsel) * LBK + chunkO];
#pragma unroll
    for (int j = 0; j < 4; ++j)
      bfr[j] = *(const bf16x8*)&lB[(wc * 64 + j * 16 + rsel) * LBK + chunkO];
#pragma unroll
    for (int i = 0; i < 4; ++i)
#pragma unroll
      for (int j = 0; j < 4; ++j)
        acc[i][j] = __builtin_amdgcn_mfma_f32_16x16x32_bf16(af[i], bfr[j], acc[i][j], 0, 0, 0);
    __syncthreads();
  }

  // ---- epilogue: bias + leaky into LDS tile [128][128] bf16 ----
  // C/D layout: col=lane&15, row=(lane>>4)*4+reg (m89-verified)
  const int rbase = (lane >> 4) * 4;
  const int csel = lane & 15;
#pragma unroll
  for (int i = 0; i < 4; ++i) {
#pragma unroll
    for (int j = 0; j < 4; ++j) {
      const int col = wc * 64 + j * 16 + csel;
      const float bv = bias[n0 + col];
#pragma unroll
      for (int q = 0; q < 4; ++q) {
        const int row = wr * 64 + i * 16 + rbase + q;
        float v = acc[i][j][q] + bv;
        v = (v > 0.f) ? v : 0.01f * v;
        smem[row * LBN + col] = f2b(v);
      }
    }
  }
  __syncthreads();

  // ---- coalesced store: 16 lanes x 16B = 256B contiguous per row ----
  const int chunk = tid & 15;  // 16B chunk within the 128-col slab
#pragma unroll
  for (int it = 0; it < 8; ++it) {
    const int row = it * 16 + (tid >> 4);
    const uint4 vv = *(const uint4*)&smem[row * LBN + chunk * 8];
    *(uint4*)(Obf + (m0 + row) * D + n0 + chunk * 8) = vv;
    if (Of32) {
      float4 f0, f1;
      f0.x = b_lo(vv.x); f0.y = b_hi(vv.x); f0.z = b_lo(vv.y); f0.w = b_hi(vv.y);
      f1.x = b_lo(vv.z); f1.y = b_hi(vv.z); f1.z = b_lo(vv.w); f1.w = b_hi(vv.w);
      float* op = Of32 + (m0 + row) * D + n0 + chunk * 8;
      *(float4*)op = f0;
      *(float4*)(op + 4) = f1;
    }
  }
}

// ------------------------- segment max (pooling) ---------------------------
__global__ __launch_bounds__(256) void segmax_partial(const ushort* __restrict__ xb,
                                                      const int* __restrict__ gstart,
                                                      float* __restrict__ partial) {
  const int g = blockIdx.x, s = blockIdx.y, t = threadIdx.x;
  const int st = gstart[g], en = gstart[g + 1];
  const long long cnt = en - st;
  const int lo = st + (int)((cnt * s) >> 3);
  const int hi = st + (int)((cnt * (s + 1)) >> 3);
  float m0 = -3.4e38f, m1 = -3.4e38f;
  for (int n = lo; n < hi; ++n) {
    const uint u = *(const uint*)(xb + (size_t)n * D + t * 2);
    m0 = fmaxf(m0, b_lo(u));
    m1 = fmaxf(m1, b_hi(u));
  }
  float* p = partial + (size_t)(g * 8 + s) * D + t * 2;
  p[0] = m0;
  p[1] = m1;
}

__global__ void segmax_combine(const float* __restrict__ partial, float* __restrict__ maxval) {
  const int i = blockIdx.x * 256 + threadIdx.x;  // < B*D
  const int g = i >> 9, d0 = i & (D - 1);
  float m = partial[(size_t)(g * 8) * D + d0];
#pragma unroll
  for (int s = 1; s < 8; ++s) m = fmaxf(m, partial[(size_t)(g * 8 + s) * D + d0]);
  maxval[i] = m;
}

// -------- part (+)= maxval @ W + bias  (f32, W is [k][o] row-major) --------
__global__ __launch_bounds__(256) void pool_gemm(const float* __restrict__ maxval,
                                                 const float* __restrict__ Wp,
                                                 const float* __restrict__ bias,
                                                 float* __restrict__ part, int accumulate) {
  const int g = blockIdx.x;
  const int o = blockIdx.y * 256 + threadIdx.x;
  const float* mrow = maxval + (size_t)g * D;
  float acc = bias[o];
#pragma unroll 8
  for (int k = 0; k < D; ++k) acc = fmaf(mrow[k], Wp[(size_t)k * D + o], acc);
  const size_t idx = (size_t)g * D + o;
  part[idx] = accumulate ? part[idx] + acc : acc;
}

// ---------------------------------------------------------------------------
extern "C" void kernel_launch(void* const* d_in, const int* in_sizes, int n_in,
                              void* d_out, int out_size, void* d_ws, size_t ws_size,
                              hipStream_t stream) {
  const float* x = (const float*)d_in[0];
  const int* ei = (const int*)d_in[1];
  const int* batch = (const int*)d_in[2];
  const float* proj_w = (const float*)d_in[3];
  const float* proj_b = (const float*)d_in[4];
  const float* lin1_w = (const float*)d_in[5];
  const float* lin1_b = (const float*)d_in[6];
  const float* lin2_w = (const float*)d_in[7];
  const float* lin2_b = (const float*)d_in[8];
  const float* eps = (const float*)d_in[9];
  const float* pool_w = (const float*)d_in[10];
  const float* pool_b = (const float*)d_in[11];

  const int N = in_sizes[0] / D;  // 65536
  const int E = in_sizes[1] / 2;  // 524288
  const int B = 64;
  const int* src = ei;
  const int* dst = ei + E;

  float* part = (float*)d_out;         // [64][512]
  float* xout = part + (size_t)B * D;  // [N][512]

  // workspace carve (~209 MB)
  char* w = (char*)d_ws;
  ushort* xb = (ushort*)w;   w += (size_t)N * D * 2;
  ushort* hb = (ushort*)w;   w += (size_t)N * D * 2;
  ushort* tb = (ushort*)w;   w += (size_t)N * D * 2;
  ushort* l1bt = (ushort*)w; w += (size_t)3 * D * D * 2;
  ushort* l2bt = (ushort*)w; w += (size_t)3 * D * D * 2;
  int* rowptr = (int*)w;     w += (size_t)(N + 4) * 4;
  int* cursor = (int*)w;     w += (size_t)N * 4;
  int* deg = (int*)w;        w += (size_t)N * 4;
  int* csr = (int*)w;        w += (size_t)E * 4;
  int* bsum = (int*)w;       w += 256 * 4;
  int* gstart = (int*)w;     w += 128 * 4;
  float* partial = (float*)w; w += (size_t)B * 8 * D * 4;
  float* maxval = (float*)w;  w += (size_t)B * D * 4;
  (void)ws_size; (void)n_in; (void)out_size;

  (void)hipMemsetAsync(deg, 0, (size_t)N * 4, stream);
  f32_to_bf16_vec<<<(N * (D / 8) + 255) / 256, 256, 0, stream>>>(x, xb, N * (D / 8));
  for (int l = 0; l < 3; ++l) {
    transpose_bf16<<<dim3(8, 8), 256, 0, stream>>>(lin1_w + (size_t)l * D * D,
                                                   l1bt + (size_t)l * D * D);
    transpose_bf16<<<dim3(8, 8), 256, 0, stream>>>(lin2_w + (size_t)l * D * D,
                                                   l2bt + (size_t)l * D * D);
  }
  count_deg<<<(E + 255) / 256, 256, 0, stream>>>(dst, deg, E);
  scan_block<<<N / 256, 256, 0, stream>>>(deg, rowptr, bsum);
  scan_block<<<1, 256, 0, stream>>>(bsum, bsum, (int*)nullptr);
  scan_fixup<<<N / 256, 256, 0, stream>>>(rowptr, bsum, cursor, N, E);
  fill_csr<<<(E + 255) / 256, 256, 0, stream>>>(src, dst, cursor, csr, E);
  compute_gstart<<<(N + 255) / 256, 256, 0, stream>>>(batch, gstart, N, B);

  // part = segmax(x) @ proj_w + proj_b
  segmax_partial<<<dim3(B, 8), 256, 0, stream>>>(xb, gstart, partial);
  segmax_combine<<<B * D / 256, 256, 0, stream>>>(partial, maxval);
  pool_gemm<<<dim3(B, 2), 256, 0, stream>>>(maxval, proj_w, proj_b, part, 0);

  for (int l = 0; l < 3; ++l) {
    agg_kernel<<<N / 4, 256, 0, stream>>>(xb, rowptr, csr, eps, l, hb);
    gemm_bias_leaky<<<dim3(D / LBN, N / LBM), 256, 0, stream>>>(
        hb, l1bt + (size_t)l * D * D, lin1_b + (size_t)l * D, tb, nullptr);
    gemm_bias_leaky<<<dim3(D / LBN, N / LBM), 256, 0, stream>>>(
        tb, l2bt + (size_t)l * D * D, lin2_b + (size_t)l * D, xb,
        (l == 2) ? xout : nullptr);
    segmax_partial<<<dim3(B, 8), 256, 0, stream>>>(xb, gstart, partial);
    segmax_combine<<<B * D / 256, 256, 0, stream>>>(partial, maxval);
    pool_gemm<<<dim3(B, 2), 256, 0, stream>>>(maxval, pool_w + (size_t)l * D * D,
                                              pool_b + (size_t)l * D, part, 1);
  }
}

// Round 5
// 974.187 us; speedup vs baseline: 1.1001x; 1.0229x over previous
//
#include <hip/hip_runtime.h>

typedef unsigned int uint;
typedef unsigned short ushort;

#define D 512
#define LBM 128
#define LBN 128
#define LBK 64

typedef __attribute__((ext_vector_type(8))) short bf16x8;
typedef __attribute__((ext_vector_type(4))) float f32x4;

__device__ __forceinline__ ushort f2b(float f) {
  uint u = __builtin_bit_cast(uint, f);
  return (ushort)((u + 0x7FFFu + ((u >> 16) & 1u)) >> 16);  // RNE
}
__device__ __forceinline__ float b_lo(uint u) { return __builtin_bit_cast(float, u << 16); }
__device__ __forceinline__ float b_hi(uint u) { return __builtin_bit_cast(float, u & 0xFFFF0000u); }

__device__ __forceinline__ void gload16(const void* g, void* l) {
  __builtin_amdgcn_global_load_lds((const __attribute__((address_space(1))) void*)g,
                                   (__attribute__((address_space(3))) void*)l, 16, 0, 0);
}

// ---------------- f32 -> bf16 bulk convert (8 elems/thread) ----------------
__global__ __launch_bounds__(256) void f32_to_bf16_vec(const float* __restrict__ in,
                                                       ushort* __restrict__ out, int n8) {
  const int i = blockIdx.x * 256 + threadIdx.x;
  if (i >= n8) return;
  const float4* p = (const float4*)in + (size_t)i * 2;
  float4 a = p[0], b = p[1];
  uint4 o;
  o.x = f2b(a.x) | ((uint)f2b(a.y) << 16);
  o.y = f2b(a.z) | ((uint)f2b(a.w) << 16);
  o.z = f2b(b.x) | ((uint)f2b(b.y) << 16);
  o.w = f2b(b.z) | ((uint)f2b(b.w) << 16);
  ((uint4*)out)[i] = o;
}

// ------------- transpose 512x512 f32 [k][o] -> bf16 BT [o][k] --------------
__global__ __launch_bounds__(256) void transpose_bf16(const float* __restrict__ W,
                                                      ushort* __restrict__ BT) {
  __shared__ float tile[64][65];
  const int bk = blockIdx.x * 64;  // k block
  const int bo = blockIdx.y * 64;  // o block
  const int tx = threadIdx.x & 63, ty = threadIdx.x >> 6;
#pragma unroll
  for (int r = 0; r < 64; r += 4)
    tile[r + ty][tx] = W[(size_t)(bk + r + ty) * D + bo + tx];
  __syncthreads();
#pragma unroll
  for (int r = 0; r < 64; r += 4)
    BT[(size_t)(bo + r + ty) * D + bk + tx] = f2b(tile[tx][r + ty]);
}

// ---------------------------- CSR build ------------------------------------
__global__ void count_deg(const int* __restrict__ dst, int* __restrict__ deg, int E) {
  const int e = blockIdx.x * 256 + threadIdx.x;
  if (e < E) atomicAdd(&deg[dst[e]], 1);
}

__global__ __launch_bounds__(256) void scan_block(const int* __restrict__ in,
                                                  int* __restrict__ out,
                                                  int* __restrict__ bsum) {
  __shared__ int sm[256];
  const int t = threadIdx.x;
  const int gi = blockIdx.x * 256 + t;
  const int v = in[gi];
  int x = v;
  sm[t] = x;
  __syncthreads();
#pragma unroll
  for (int off = 1; off < 256; off <<= 1) {
    const int y = (t >= off) ? sm[t - off] : 0;
    __syncthreads();
    x += y;
    sm[t] = x;
    __syncthreads();
  }
  out[gi] = x - v;  // exclusive
  if (t == 255 && bsum) bsum[blockIdx.x] = x;
}

__global__ void scan_fixup(int* __restrict__ rowptr, const int* __restrict__ bsum,
                           int* __restrict__ cursor, int N, int E) {
  const int i = blockIdx.x * 256 + threadIdx.x;
  const int r = rowptr[i] + bsum[i >> 8];
  rowptr[i] = r;
  cursor[i] = r;
  if (i == 0) rowptr[N] = E;
}

__global__ void fill_csr(const int* __restrict__ src, const int* __restrict__ dst,
                         int* __restrict__ cursor, int* __restrict__ csr, int E) {
  const int e = blockIdx.x * 256 + threadIdx.x;
  if (e >= E) return;
  const int pos = atomicAdd(&cursor[dst[e]], 1);
  csr[pos] = src[e];
}

// ------------------- graph start offsets (batch is sorted) -----------------
__global__ void compute_gstart(const int* __restrict__ batch, int* __restrict__ gstart,
                               int N, int B) {
  const int n = blockIdx.x * 256 + threadIdx.x;
  if (n >= N) return;
  const int b = batch[n];
  const int bp = (n == 0) ? -1 : batch[n - 1];
  for (int x = bp + 1; x <= b; ++x) gstart[x] = n;
  if (n == N - 1)
    for (int x = b + 1; x <= B; ++x) gstart[x] = N;
}

// --------------- GIN aggregation: h = (1+eps)*x + sum_nbr x ----------------
// One wave per node. Bounded by per-CU outstanding-miss capacity x latency on
// the random row gather (~3.8 TB/s fetch); FETCH ~282MB is at the structural
// floor for random src across 8 XCD L2s. Do not touch (R2/R4 A/B: neutral).
#define ACC8(v)                                          \
  a[0] += b_lo((v).x); a[1] += b_hi((v).x);              \
  a[2] += b_lo((v).y); a[3] += b_hi((v).y);              \
  a[4] += b_lo((v).z); a[5] += b_hi((v).z);              \
  a[6] += b_lo((v).w); a[7] += b_hi((v).w)

__global__ __launch_bounds__(256) void agg_kernel(const ushort* __restrict__ xb,
                                                  const int* __restrict__ rowptr,
                                                  const int* __restrict__ csr,
                                                  const float* __restrict__ eps_arr,
                                                  int layer, ushort* __restrict__ h) {
  const int node = blockIdx.x * 4 + (threadIdx.x >> 6);
  const int lane = threadIdx.x & 63;
  const float sc = 1.0f + eps_arr[layer];
  const size_t off = (size_t)lane * 8;
  const size_t base = (size_t)node * D + off;
  const uint4 u = *(const uint4*)(xb + base);
  float a[8];
  a[0] = b_lo(u.x) * sc; a[1] = b_hi(u.x) * sc;
  a[2] = b_lo(u.y) * sc; a[3] = b_hi(u.y) * sc;
  a[4] = b_lo(u.z) * sc; a[5] = b_hi(u.z) * sc;
  a[6] = b_lo(u.w) * sc; a[7] = b_hi(u.w) * sc;
  int e = rowptr[node];
  const int en = rowptr[node + 1];
  for (; e + 4 <= en; e += 4) {
    const int s0 = csr[e], s1 = csr[e + 1], s2 = csr[e + 2], s3 = csr[e + 3];
    const uint4 v0 = *(const uint4*)(xb + (size_t)s0 * D + off);
    const uint4 v1 = *(const uint4*)(xb + (size_t)s1 * D + off);
    const uint4 v2 = *(const uint4*)(xb + (size_t)s2 * D + off);
    const uint4 v3 = *(const uint4*)(xb + (size_t)s3 * D + off);
    ACC8(v0); ACC8(v1); ACC8(v2); ACC8(v3);
  }
  if (e + 2 <= en) {
    const int s0 = csr[e], s1 = csr[e + 1];
    const uint4 v0 = *(const uint4*)(xb + (size_t)s0 * D + off);
    const uint4 v1 = *(const uint4*)(xb + (size_t)s1 * D + off);
    ACC8(v0); ACC8(v1);
    e += 2;
  }
  if (e < en) {
    const int s0 = csr[e];
    const uint4 v0 = *(const uint4*)(xb + (size_t)s0 * D + off);
    ACC8(v0);
  }
  uint4 o;
  o.x = f2b(a[0]) | ((uint)f2b(a[1]) << 16);
  o.y = f2b(a[2]) | ((uint)f2b(a[3]) << 16);
  o.z = f2b(a[4]) | ((uint)f2b(a[5]) << 16);
  o.w = f2b(a[6]) | ((uint)f2b(a[7]) << 16);
  *(uint4*)(h + base) = o;
}

// --------- bf16 GEMM: O = leaky(A @ BT^T + bias), BK=64 ---------------------
// A [M][512] bf16 row-major, BT [512][512] bf16 with BT[o][k] = W[k][o].
// BK=64: halves drain-barrier count vs BK=32 (K=512 -> 8 iters), same 32KB LDS.
// Row = 128B = all 32 banks, so unswizzled fragment reads would be 16-way
// conflicted. XOR swizzle (rule 21, both sides):
//   LDS[row][chunk] holds global chunk  chunk ^ (row&7)   (chunk = 8 ushorts)
// staged via permuted GLOBAL source (linear gload_lds dest), read back with
// the same XOR -> every bank touched exactly 2x per 16-lane phase (free).
__global__ __launch_bounds__(256) void gemm_bias_leaky(const ushort* __restrict__ A,
                                                       const ushort* __restrict__ BT,
                                                       const float* __restrict__ bias,
                                                       ushort* __restrict__ Obf,
                                                       float* __restrict__ Of32) {
  __shared__ alignas(16) ushort smem[LBM * LBN];  // 32 KB
  ushort* lA = smem;                    // [128 rows][64] swizzled, 16 KB
  ushort* lB = smem + LBM * LBK;        // 16 KB

  const int tid = threadIdx.x;
  const int lane = tid & 63;
  const int wave = tid >> 6;
  const int wr = wave >> 1, wc = wave & 1;  // 2x2 waves, 64x64 each

  // XCD swizzle: contiguous chunk per XCD, col-fastest inside.
  const int lin = blockIdx.y * gridDim.x + blockIdx.x;
  const int nwg = gridDim.x * gridDim.y;
  const int wg = (lin & 7) * (nwg >> 3) + (lin >> 3);
  const int n0 = (wg & 3) * LBN;
  const size_t m0 = (size_t)(wg >> 2) * LBM;

  // staging geometry: issue i covers rows [i*32, i*32+32); thread tid handles
  // LDS linear 16B slot (i*256+tid); row/srcchunk invariant across i mod 8.
  const int srow0 = tid >> 3;                       // row for issue 0
  const int schunk = ((tid & 7) ^ (srow0 & 7)) * 8; // swizzled global chunk

  f32x4 acc[4][4] = {};

  // fragment-read addressing
  const int rsel = lane & 15;
  const int g = lane >> 4;
  const int key = rsel & 7;

  for (int kt = 0; kt < D / LBK; ++kt) {
    const int k0 = kt * LBK;
#pragma unroll
    for (int i = 0; i < 4; ++i) {
      const int row = i * 32 + srow0;
      // wave-uniform LDS base; HW adds lane*16B
      gload16(A + (m0 + row) * D + k0 + schunk, &lA[(i * 256 + wave * 64) * 8]);
      gload16(BT + (size_t)(n0 + row) * D + k0 + schunk, &lB[(i * 256 + wave * 64) * 8]);
    }
    __syncthreads();  // drains vmcnt before barrier
#pragma unroll
    for (int kk = 0; kk < 2; ++kk) {
      const int ch = ((kk * 4 + g) ^ key) * 8;
      bf16x8 af[4], bfr[4];
#pragma unroll
      for (int i = 0; i < 4; ++i)
        af[i] = *(const bf16x8*)&lA[(wr * 64 + i * 16 + rsel) * LBK + ch];
#pragma unroll
      for (int j = 0; j < 4; ++j)
        bfr[j] = *(const bf16x8*)&lB[(wc * 64 + j * 16 + rsel) * LBK + ch];
#pragma unroll
      for (int i = 0; i < 4; ++i)
#pragma unroll
        for (int j = 0; j < 4; ++j)
          acc[i][j] = __builtin_amdgcn_mfma_f32_16x16x32_bf16(af[i], bfr[j], acc[i][j], 0, 0, 0);
    }
    __syncthreads();
  }

  // ---- epilogue: bias + leaky into LDS tile [128][128] bf16 ----
  // C/D layout: col=lane&15, row=(lane>>4)*4+reg (m89-verified)
  const int rbase = (lane >> 4) * 4;
  const int csel = lane & 15;
#pragma unroll
  for (int i = 0; i < 4; ++i) {
#pragma unroll
    for (int j = 0; j < 4; ++j) {
      const int col = wc * 64 + j * 16 + csel;
      const float bv = bias[n0 + col];
#pragma unroll
      for (int q = 0; q < 4; ++q) {
        const int row = wr * 64 + i * 16 + rbase + q;
        float v = acc[i][j][q] + bv;
        v = (v > 0.f) ? v : 0.01f * v;
        smem[row * LBN + col] = f2b(v);
      }
    }
  }
  __syncthreads();

  // ---- coalesced store: 16 lanes x 16B = 256B contiguous per row ----
  const int chunk = tid & 15;  // 16B chunk within the 128-col slab
#pragma unroll
  for (int it = 0; it < 8; ++it) {
    const int row = it * 16 + (tid >> 4);
    const uint4 vv = *(const uint4*)&smem[row * LBN + chunk * 8];
    *(uint4*)(Obf + (m0 + row) * D + n0 + chunk * 8) = vv;
    if (Of32) {
      float4 f0, f1;
      f0.x = b_lo(vv.x); f0.y = b_hi(vv.x); f0.z = b_lo(vv.y); f0.w = b_hi(vv.y);
      f1.x = b_lo(vv.z); f1.y = b_hi(vv.z); f1.z = b_lo(vv.w); f1.w = b_hi(vv.w);
      float* op = Of32 + (m0 + row) * D + n0 + chunk * 8;
      *(float4*)op = f0;
      *(float4*)(op + 4) = f1;
    }
  }
}

// ------------------------- segment max (pooling) ---------------------------
__global__ __launch_bounds__(256) void segmax_partial(const ushort* __restrict__ xb,
                                                      const int* __restrict__ gstart,
                                                      float* __restrict__ partial) {
  const int g = blockIdx.x, s = blockIdx.y, t = threadIdx.x;
  const int st = gstart[g], en = gstart[g + 1];
  const long long cnt = en - st;
  const int lo = st + (int)((cnt * s) >> 3);
  const int hi = st + (int)((cnt * (s + 1)) >> 3);
  float m0 = -3.4e38f, m1 = -3.4e38f;
  for (int n = lo; n < hi; ++n) {
    const uint u = *(const uint*)(xb + (size_t)n * D + t * 2);
    m0 = fmaxf(m0, b_lo(u));
    m1 = fmaxf(m1, b_hi(u));
  }
  float* p = partial + (size_t)(g * 8 + s) * D + t * 2;
  p[0] = m0;
  p[1] = m1;
}

__global__ void segmax_combine(const float* __restrict__ partial, float* __restrict__ maxval) {
  const int i = blockIdx.x * 256 + threadIdx.x;  // < B*D
  const int g = i >> 9, d0 = i & (D - 1);
  float m = partial[(size_t)(g * 8) * D + d0];
#pragma unroll
  for (int s = 1; s < 8; ++s) m = fmaxf(m, partial[(size_t)(g * 8 + s) * D + d0]);
  maxval[i] = m;
}

// -------- part (+)= maxval @ W + bias  (f32, W is [k][o] row-major) --------
__global__ __launch_bounds__(256) void pool_gemm(const float* __restrict__ maxval,
                                                 const float* __restrict__ Wp,
                                                 const float* __restrict__ bias,
                                                 float* __restrict__ part, int accumulate) {
  const int g = blockIdx.x;
  const int o = blockIdx.y * 256 + threadIdx.x;
  const float* mrow = maxval + (size_t)g * D;
  float acc = bias[o];
#pragma unroll 8
  for (int k = 0; k < D; ++k) acc = fmaf(mrow[k], Wp[(size_t)k * D + o], acc);
  const size_t idx = (size_t)g * D + o;
  part[idx] = accumulate ? part[idx] + acc : acc;
}

// ---------------------------------------------------------------------------
extern "C" void kernel_launch(void* const* d_in, const int* in_sizes, int n_in,
                              void* d_out, int out_size, void* d_ws, size_t ws_size,
                              hipStream_t stream) {
  const float* x = (const float*)d_in[0];
  const int* ei = (const int*)d_in[1];
  const int* batch = (const int*)d_in[2];
  const float* proj_w = (const float*)d_in[3];
  const float* proj_b = (const float*)d_in[4];
  const float* lin1_w = (const float*)d_in[5];
  const float* lin1_b = (const float*)d_in[6];
  const float* lin2_w = (const float*)d_in[7];
  const float* lin2_b = (const float*)d_in[8];
  const float* eps = (const float*)d_in[9];
  const float* pool_w = (const float*)d_in[10];
  const float* pool_b = (const float*)d_in[11];

  const int N = in_sizes[0] / D;  // 65536
  const int E = in_sizes[1] / 2;  // 524288
  const int B = 64;
  const int* src = ei;
  const int* dst = ei + E;

  float* part = (float*)d_out;         // [64][512]
  float* xout = part + (size_t)B * D;  // [N][512]

  // workspace carve (~209 MB)
  char* w = (char*)d_ws;
  ushort* xb = (ushort*)w;   w += (size_t)N * D * 2;
  ushort* hb = (ushort*)w;   w += (size_t)N * D * 2;
  ushort* tb = (ushort*)w;   w += (size_t)N * D * 2;
  ushort* l1bt = (ushort*)w; w += (size_t)3 * D * D * 2;
  ushort* l2bt = (ushort*)w; w += (size_t)3 * D * D * 2;
  int* rowptr = (int*)w;     w += (size_t)(N + 4) * 4;
  int* cursor = (int*)w;     w += (size_t)N * 4;
  int* deg = (int*)w;        w += (size_t)N * 4;
  int* csr = (int*)w;        w += (size_t)E * 4;
  int* bsum = (int*)w;       w += 256 * 4;
  int* gstart = (int*)w;     w += 128 * 4;
  float* partial = (float*)w; w += (size_t)B * 8 * D * 4;
  float* maxval = (float*)w;  w += (size_t)B * D * 4;
  (void)ws_size; (void)n_in; (void)out_size;

  (void)hipMemsetAsync(deg, 0, (size_t)N * 4, stream);
  f32_to_bf16_vec<<<(N * (D / 8) + 255) / 256, 256, 0, stream>>>(x, xb, N * (D / 8));
  for (int l = 0; l < 3; ++l) {
    transpose_bf16<<<dim3(8, 8), 256, 0, stream>>>(lin1_w + (size_t)l * D * D,
                                                   l1bt + (size_t)l * D * D);
    transpose_bf16<<<dim3(8, 8), 256, 0, stream>>>(lin2_w + (size_t)l * D * D,
                                                   l2bt + (size_t)l * D * D);
  }
  count_deg<<<(E + 255) / 256, 256, 0, stream>>>(dst, deg, E);
  scan_block<<<N / 256, 256, 0, stream>>>(deg, rowptr, bsum);
  scan_block<<<1, 256, 0, stream>>>(bsum, bsum, (int*)nullptr);
  scan_fixup<<<N / 256, 256, 0, stream>>>(rowptr, bsum, cursor, N, E);
  fill_csr<<<(E + 255) / 256, 256, 0, stream>>>(src, dst, cursor, csr, E);
  compute_gstart<<<(N + 255) / 256, 256, 0, stream>>>(batch, gstart, N, B);

  // part = segmax(x) @ proj_w + proj_b
  segmax_partial<<<dim3(B, 8), 256, 0, stream>>>(xb, gstart, partial);
  segmax_combine<<<B * D / 256, 256, 0, stream>>>(partial, maxval);
  pool_gemm<<<dim3(B, 2), 256, 0, stream>>>(maxval, proj_w, proj_b, part, 0);

  for (int l = 0; l < 3; ++l) {
    agg_kernel<<<N / 4, 256, 0, stream>>>(xb, rowptr, csr, eps, l, hb);
    gemm_bias_leaky<<<dim3(D / LBN, N / LBM), 256, 0, stream>>>(
        hb, l1bt + (size_t)l * D * D, lin1_b + (size_t)l * D, tb, nullptr);
    gemm_bias_leaky<<<dim3(D / LBN, N / LBM), 256, 0, stream>>>(
        tb, l2bt + (size_t)l * D * D, lin2_b + (size_t)l * D, xb,
        (l == 2) ? xout : nullptr);
    segmax_partial<<<dim3(B, 8), 256, 0, stream>>>(xb, gstart, partial);
    segmax_combine<<<B * D / 256, 256, 0, stream>>>(partial, maxval);
    pool_gemm<<<dim3(B, 2), 256, 0, stream>>>(maxval, pool_w + (size_t)l * D * D,
                                              pool_b + (size_t)l * D, part, 1);
  }
}

// Round 6
// 964.003 us; speedup vs baseline: 1.1117x; 1.0106x over previous
//
#include <hip/hip_runtime.h>

typedef unsigned int uint;
typedef unsigned short ushort;

#define D 512
#define LBM 128
#define LBN 128
#define LBK 64

typedef __attribute__((ext_vector_type(8))) short bf16x8;
typedef __attribute__((ext_vector_type(4))) float f32x4;

__device__ __forceinline__ ushort f2b(float f) {
  uint u = __builtin_bit_cast(uint, f);
  return (ushort)((u + 0x7FFFu + ((u >> 16) & 1u)) >> 16);  // RNE
}
__device__ __forceinline__ float b_lo(uint u) { return __builtin_bit_cast(float, u << 16); }
__device__ __forceinline__ float b_hi(uint u) { return __builtin_bit_cast(float, u & 0xFFFF0000u); }

__device__ __forceinline__ void gload16(const void* g, void* l) {
  __builtin_amdgcn_global_load_lds((const __attribute__((address_space(1))) void*)g,
                                   (__attribute__((address_space(3))) void*)l, 16, 0, 0);
}

// ---------------- f32 -> bf16 bulk convert (8 elems/thread) ----------------
__global__ __launch_bounds__(256) void f32_to_bf16_vec(const float* __restrict__ in,
                                                       ushort* __restrict__ out, int n8) {
  const int i = blockIdx.x * 256 + threadIdx.x;
  if (i >= n8) return;
  const float4* p = (const float4*)in + (size_t)i * 2;
  float4 a = p[0], b = p[1];
  uint4 o;
  o.x = f2b(a.x) | ((uint)f2b(a.y) << 16);
  o.y = f2b(a.z) | ((uint)f2b(a.w) << 16);
  o.z = f2b(b.x) | ((uint)f2b(b.y) << 16);
  o.w = f2b(b.z) | ((uint)f2b(b.w) << 16);
  ((uint4*)out)[i] = o;
}

// ------------- transpose 512x512 f32 [k][o] -> bf16 BT [o][k] --------------
__global__ __launch_bounds__(256) void transpose_bf16(const float* __restrict__ W,
                                                      ushort* __restrict__ BT) {
  __shared__ float tile[64][65];
  const int bk = blockIdx.x * 64;  // k block
  const int bo = blockIdx.y * 64;  // o block
  const int tx = threadIdx.x & 63, ty = threadIdx.x >> 6;
#pragma unroll
  for (int r = 0; r < 64; r += 4)
    tile[r + ty][tx] = W[(size_t)(bk + r + ty) * D + bo + tx];
  __syncthreads();
#pragma unroll
  for (int r = 0; r < 64; r += 4)
    BT[(size_t)(bo + r + ty) * D + bk + tx] = f2b(tile[tx][r + ty]);
}

// ---------------------------- CSR build ------------------------------------
__global__ void count_deg(const int* __restrict__ dst, int* __restrict__ deg, int E) {
  const int e = blockIdx.x * 256 + threadIdx.x;
  if (e < E) atomicAdd(&deg[dst[e]], 1);
}

__global__ __launch_bounds__(256) void scan_block(const int* __restrict__ in,
                                                  int* __restrict__ out,
                                                  int* __restrict__ bsum) {
  __shared__ int sm[256];
  const int t = threadIdx.x;
  const int gi = blockIdx.x * 256 + t;
  const int v = in[gi];
  int x = v;
  sm[t] = x;
  __syncthreads();
#pragma unroll
  for (int off = 1; off < 256; off <<= 1) {
    const int y = (t >= off) ? sm[t - off] : 0;
    __syncthreads();
    x += y;
    sm[t] = x;
    __syncthreads();
  }
  out[gi] = x - v;  // exclusive
  if (t == 255 && bsum) bsum[blockIdx.x] = x;
}

__global__ void scan_fixup(int* __restrict__ rowptr, const int* __restrict__ bsum,
                           int* __restrict__ cursor, int N, int E) {
  const int i = blockIdx.x * 256 + threadIdx.x;
  const int r = rowptr[i] + bsum[i >> 8];
  rowptr[i] = r;
  cursor[i] = r;
  if (i == 0) rowptr[N] = E;
}

__global__ void fill_csr(const int* __restrict__ src, const int* __restrict__ dst,
                         int* __restrict__ cursor, int* __restrict__ csr, int E) {
  const int e = blockIdx.x * 256 + threadIdx.x;
  if (e >= E) return;
  const int pos = atomicAdd(&cursor[dst[e]], 1);
  csr[pos] = src[e];
}

// ------------------- graph start offsets (batch is sorted) -----------------
__global__ void compute_gstart(const int* __restrict__ batch, int* __restrict__ gstart,
                               int N, int B) {
  const int n = blockIdx.x * 256 + threadIdx.x;
  if (n >= N) return;
  const int b = batch[n];
  const int bp = (n == 0) ? -1 : batch[n - 1];
  for (int x = bp + 1; x <= b; ++x) gstart[x] = n;
  if (n == N - 1)
    for (int x = b + 1; x <= B; ++x) gstart[x] = N;
}

// --------------- GIN aggregation: h = (1+eps)*x + sum_nbr x ----------------
// One wave per node. Bounded by per-CU outstanding-miss capacity x latency on
// the random row gather (~3.8 TB/s fetch); FETCH ~282MB is at the structural
// floor for random src across 8 XCD L2s. Do not touch (R2/R4 A/B: neutral).
#define ACC8(v)                                          \
  a[0] += b_lo((v).x); a[1] += b_hi((v).x);              \
  a[2] += b_lo((v).y); a[3] += b_hi((v).y);              \
  a[4] += b_lo((v).z); a[5] += b_hi((v).z);              \
  a[6] += b_lo((v).w); a[7] += b_hi((v).w)

__global__ __launch_bounds__(256) void agg_kernel(const ushort* __restrict__ xb,
                                                  const int* __restrict__ rowptr,
                                                  const int* __restrict__ csr,
                                                  const float* __restrict__ eps_arr,
                                                  int layer, ushort* __restrict__ h) {
  const int node = blockIdx.x * 4 + (threadIdx.x >> 6);
  const int lane = threadIdx.x & 63;
  const float sc = 1.0f + eps_arr[layer];
  const size_t off = (size_t)lane * 8;
  const size_t base = (size_t)node * D + off;
  const uint4 u = *(const uint4*)(xb + base);
  float a[8];
  a[0] = b_lo(u.x) * sc; a[1] = b_hi(u.x) * sc;
  a[2] = b_lo(u.y) * sc; a[3] = b_hi(u.y) * sc;
  a[4] = b_lo(u.z) * sc; a[5] = b_hi(u.z) * sc;
  a[6] = b_lo(u.w) * sc; a[7] = b_hi(u.w) * sc;
  int e = rowptr[node];
  const int en = rowptr[node + 1];
  for (; e + 4 <= en; e += 4) {
    const int s0 = csr[e], s1 = csr[e + 1], s2 = csr[e + 2], s3 = csr[e + 3];
    const uint4 v0 = *(const uint4*)(xb + (size_t)s0 * D + off);
    const uint4 v1 = *(const uint4*)(xb + (size_t)s1 * D + off);
    const uint4 v2 = *(const uint4*)(xb + (size_t)s2 * D + off);
    const uint4 v3 = *(const uint4*)(xb + (size_t)s3 * D + off);
    ACC8(v0); ACC8(v1); ACC8(v2); ACC8(v3);
  }
  if (e + 2 <= en) {
    const int s0 = csr[e], s1 = csr[e + 1];
    const uint4 v0 = *(const uint4*)(xb + (size_t)s0 * D + off);
    const uint4 v1 = *(const uint4*)(xb + (size_t)s1 * D + off);
    ACC8(v0); ACC8(v1);
    e += 2;
  }
  if (e < en) {
    const int s0 = csr[e];
    const uint4 v0 = *(const uint4*)(xb + (size_t)s0 * D + off);
    ACC8(v0);
  }
  uint4 o;
  o.x = f2b(a[0]) | ((uint)f2b(a[1]) << 16);
  o.y = f2b(a[2]) | ((uint)f2b(a[3]) << 16);
  o.z = f2b(a[4]) | ((uint)f2b(a[5]) << 16);
  o.w = f2b(a[6]) | ((uint)f2b(a[7]) << 16);
  *(uint4*)(h + base) = o;
}

// --------- bf16 GEMM: O = leaky(A @ BT^T + bias), BK=64, 2-phase dbuf ------
// A [M][512] bf16 row-major, BT [512][512] bf16 with BT[o][k] = W[k][o].
// T3-minimum schedule: STAGE(next tile -> other buffer) BEFORE compute of the
// current tile; the end-of-iter __syncthreads() drains vmcnt after compute,
// so stage latency hides under ds_read+MFMA instead of being fully exposed
// (R1-R5 structure: stage -> drain -> compute, MfmaUtil 14%).
// XOR swizzle (rule 21, both sides): LDS[row][chunk] holds global chunk
// chunk ^ (row&7); staged via permuted GLOBAL source (linear gload_lds dest),
// read with the same XOR -> conflict-free fragment reads.
__global__ __launch_bounds__(256) void gemm_bias_leaky(const ushort* __restrict__ A,
                                                       const ushort* __restrict__ BT,
                                                       const float* __restrict__ bias,
                                                       ushort* __restrict__ Obf,
                                                       float* __restrict__ Of32) {
  __shared__ alignas(16) ushort smem[4 * LBM * LBK];  // 64 KB: A0,B0,A1,B1
  ushort* const lA0 = smem;
  ushort* const lB0 = smem + LBM * LBK;
  ushort* const lA1 = smem + 2 * LBM * LBK;
  ushort* const lB1 = smem + 3 * LBM * LBK;

  const int tid = threadIdx.x;
  const int lane = tid & 63;
  const int wave = tid >> 6;
  const int wr = wave >> 1, wc = wave & 1;  // 2x2 waves, 64x64 each

  // XCD swizzle: contiguous chunk per XCD, col-fastest inside.
  const int lin = blockIdx.y * gridDim.x + blockIdx.x;
  const int nwg = gridDim.x * gridDim.y;
  const int wg = (lin & 7) * (nwg >> 3) + (lin >> 3);
  const int n0 = (wg & 3) * LBN;
  const size_t m0 = (size_t)(wg >> 2) * LBM;

  // staging geometry: issue i covers rows [i*32, i*32+32); thread tid handles
  // LDS linear 16B slot (i*256+tid); row%8 / srcchunk invariant across i.
  const int srow0 = tid >> 3;                        // row for issue 0
  const int schunk = ((tid & 7) ^ (srow0 & 7)) * 8;  // swizzled global chunk

  f32x4 acc[4][4] = {};

  // fragment-read addressing
  const int rsel = lane & 15;
  const int g = lane >> 4;
  const int key = rsel & 7;

#define STAGE(bufA, bufB, kt)                                                     \
  {                                                                               \
    const int k0_ = (kt) * LBK;                                                   \
    _Pragma("unroll") for (int i_ = 0; i_ < 4; ++i_) {                            \
      const int row_ = i_ * 32 + srow0;                                           \
      gload16(A + (m0 + row_) * D + k0_ + schunk, &(bufA)[(i_ * 256 + wave * 64) * 8]); \
      gload16(BT + (size_t)(n0 + row_) * D + k0_ + schunk,                        \
              &(bufB)[(i_ * 256 + wave * 64) * 8]);                               \
    }                                                                             \
  }

#define COMPUTE(bufA, bufB)                                                       \
  {                                                                               \
    _Pragma("unroll") for (int kk_ = 0; kk_ < 2; ++kk_) {                         \
      const int ch_ = ((kk_ * 4 + g) ^ key) * 8;                                  \
      bf16x8 af_[4], bf_[4];                                                      \
      _Pragma("unroll") for (int i_ = 0; i_ < 4; ++i_)                            \
          af_[i_] = *(const bf16x8*)&(bufA)[(wr * 64 + i_ * 16 + rsel) * LBK + ch_]; \
      _Pragma("unroll") for (int j_ = 0; j_ < 4; ++j_)                            \
          bf_[j_] = *(const bf16x8*)&(bufB)[(wc * 64 + j_ * 16 + rsel) * LBK + ch_]; \
      _Pragma("unroll") for (int i_ = 0; i_ < 4; ++i_)                            \
          _Pragma("unroll") for (int j_ = 0; j_ < 4; ++j_)                        \
              acc[i_][j_] = __builtin_amdgcn_mfma_f32_16x16x32_bf16(              \
                  af_[i_], bf_[j_], acc[i_][j_], 0, 0, 0);                        \
    }                                                                             \
  }

  // prologue: tile 0 -> buf0, drain, then 2-phase pairs (K=512 -> 8 tiles)
  STAGE(lA0, lB0, 0);
  __syncthreads();
#pragma unroll
  for (int ktp = 0; ktp < 4; ++ktp) {
    STAGE(lA1, lB1, 2 * ktp + 1);  // prefetch odd tile into buf1
    COMPUTE(lA0, lB0);             // compute even tile from buf0
    __syncthreads();               // drains vmcnt(0): buf1 ready
    if (ktp < 3) STAGE(lA0, lB0, 2 * ktp + 2);  // prefetch next even tile
    COMPUTE(lA1, lB1);             // compute odd tile from buf1
    __syncthreads();               // drains: buf0 ready (or all done)
  }
#undef STAGE
#undef COMPUTE

  // ---- epilogue: bias + leaky into LDS tile [128][128] bf16 (first 32KB) ----
  // C/D layout: col=lane&15, row=(lane>>4)*4+reg (m89-verified)
  const int rbase = (lane >> 4) * 4;
  const int csel = lane & 15;
#pragma unroll
  for (int i = 0; i < 4; ++i) {
#pragma unroll
    for (int j = 0; j < 4; ++j) {
      const int col = wc * 64 + j * 16 + csel;
      const float bv = bias[n0 + col];
#pragma unroll
      for (int q = 0; q < 4; ++q) {
        const int row = wr * 64 + i * 16 + rbase + q;
        float v = acc[i][j][q] + bv;
        v = (v > 0.f) ? v : 0.01f * v;
        smem[row * LBN + col] = f2b(v);
      }
    }
  }
  __syncthreads();

  // ---- coalesced store: 16 lanes x 16B = 256B contiguous per row ----
  const int chunk = tid & 15;  // 16B chunk within the 128-col slab
#pragma unroll
  for (int it = 0; it < 8; ++it) {
    const int row = it * 16 + (tid >> 4);
    const uint4 vv = *(const uint4*)&smem[row * LBN + chunk * 8];
    *(uint4*)(Obf + (m0 + row) * D + n0 + chunk * 8) = vv;
    if (Of32) {
      float4 f0, f1;
      f0.x = b_lo(vv.x); f0.y = b_hi(vv.x); f0.z = b_lo(vv.y); f0.w = b_hi(vv.y);
      f1.x = b_lo(vv.z); f1.y = b_hi(vv.z); f1.z = b_lo(vv.w); f1.w = b_hi(vv.w);
      float* op = Of32 + (m0 + row) * D + n0 + chunk * 8;
      *(float4*)op = f0;
      *(float4*)(op + 4) = f1;
    }
  }
}

// ------------------------- segment max (pooling) ---------------------------
__global__ __launch_bounds__(256) void segmax_partial(const ushort* __restrict__ xb,
                                                      const int* __restrict__ gstart,
                                                      float* __restrict__ partial) {
  const int g = blockIdx.x, s = blockIdx.y, t = threadIdx.x;
  const int st = gstart[g], en = gstart[g + 1];
  const long long cnt = en - st;
  const int lo = st + (int)((cnt * s) >> 3);
  const int hi = st + (int)((cnt * (s + 1)) >> 3);
  float m0 = -3.4e38f, m1 = -3.4e38f;
  for (int n = lo; n < hi; ++n) {
    const uint u = *(const uint*)(xb + (size_t)n * D + t * 2);
    m0 = fmaxf(m0, b_lo(u));
    m1 = fmaxf(m1, b_hi(u));
  }
  float* p = partial + (size_t)(g * 8 + s) * D + t * 2;
  p[0] = m0;
  p[1] = m1;
}

__global__ void segmax_combine(const float* __restrict__ partial, float* __restrict__ maxval) {
  const int i = blockIdx.x * 256 + threadIdx.x;  // < B*D
  const int g = i >> 9, d0 = i & (D - 1);
  float m = partial[(size_t)(g * 8) * D + d0];
#pragma unroll
  for (int s = 1; s < 8; ++s) m = fmaxf(m, partial[(size_t)(g * 8 + s) * D + d0]);
  maxval[i] = m;
}

// -------- part (+)= maxval @ W + bias  (f32, W is [k][o] row-major) --------
__global__ __launch_bounds__(256) void pool_gemm(const float* __restrict__ maxval,
                                                 const float* __restrict__ Wp,
                                                 const float* __restrict__ bias,
                                                 float* __restrict__ part, int accumulate) {
  const int g = blockIdx.x;
  const int o = blockIdx.y * 256 + threadIdx.x;
  const float* mrow = maxval + (size_t)g * D;
  float acc = bias[o];
#pragma unroll 8
  for (int k = 0; k < D; ++k) acc = fmaf(mrow[k], Wp[(size_t)k * D + o], acc);
  const size_t idx = (size_t)g * D + o;
  part[idx] = accumulate ? part[idx] + acc : acc;
}

// ---------------------------------------------------------------------------
extern "C" void kernel_launch(void* const* d_in, const int* in_sizes, int n_in,
                              void* d_out, int out_size, void* d_ws, size_t ws_size,
                              hipStream_t stream) {
  const float* x = (const float*)d_in[0];
  const int* ei = (const int*)d_in[1];
  const int* batch = (const int*)d_in[2];
  const float* proj_w = (const float*)d_in[3];
  const float* proj_b = (const float*)d_in[4];
  const float* lin1_w = (const float*)d_in[5];
  const float* lin1_b = (const float*)d_in[6];
  const float* lin2_w = (const float*)d_in[7];
  const float* lin2_b = (const float*)d_in[8];
  const float* eps = (const float*)d_in[9];
  const float* pool_w = (const float*)d_in[10];
  const float* pool_b = (const float*)d_in[11];

  const int N = in_sizes[0] / D;  // 65536
  const int E = in_sizes[1] / 2;  // 524288
  const int B = 64;
  const int* src = ei;
  const int* dst = ei + E;

  float* part = (float*)d_out;         // [64][512]
  float* xout = part + (size_t)B * D;  // [N][512]

  // workspace carve (~209 MB)
  char* w = (char*)d_ws;
  ushort* xb = (ushort*)w;   w += (size_t)N * D * 2;
  ushort* hb = (ushort*)w;   w += (size_t)N * D * 2;
  ushort* tb = (ushort*)w;   w += (size_t)N * D * 2;
  ushort* l1bt = (ushort*)w; w += (size_t)3 * D * D * 2;
  ushort* l2bt = (ushort*)w; w += (size_t)3 * D * D * 2;
  int* rowptr = (int*)w;     w += (size_t)(N + 4) * 4;
  int* cursor = (int*)w;     w += (size_t)N * 4;
  int* deg = (int*)w;        w += (size_t)N * 4;
  int* csr = (int*)w;        w += (size_t)E * 4;
  int* bsum = (int*)w;       w += 256 * 4;
  int* gstart = (int*)w;     w += 128 * 4;
  float* partial = (float*)w; w += (size_t)B * 8 * D * 4;
  float* maxval = (float*)w;  w += (size_t)B * D * 4;
  (void)ws_size; (void)n_in; (void)out_size;

  (void)hipMemsetAsync(deg, 0, (size_t)N * 4, stream);
  f32_to_bf16_vec<<<(N * (D / 8) + 255) / 256, 256, 0, stream>>>(x, xb, N * (D / 8));
  for (int l = 0; l < 3; ++l) {
    transpose_bf16<<<dim3(8, 8), 256, 0, stream>>>(lin1_w + (size_t)l * D * D,
                                                   l1bt + (size_t)l * D * D);
    transpose_bf16<<<dim3(8, 8), 256, 0, stream>>>(lin2_w + (size_t)l * D * D,
                                                   l2bt + (size_t)l * D * D);
  }
  count_deg<<<(E + 255) / 256, 256, 0, stream>>>(dst, deg, E);
  scan_block<<<N / 256, 256, 0, stream>>>(deg, rowptr, bsum);
  scan_block<<<1, 256, 0, stream>>>(bsum, bsum, (int*)nullptr);
  scan_fixup<<<N / 256, 256, 0, stream>>>(rowptr, bsum, cursor, N, E);
  fill_csr<<<(E + 255) / 256, 256, 0, stream>>>(src, dst, cursor, csr, E);
  compute_gstart<<<(N + 255) / 256, 256, 0, stream>>>(batch, gstart, N, B);

  // part = segmax(x) @ proj_w + proj_b
  segmax_partial<<<dim3(B, 8), 256, 0, stream>>>(xb, gstart, partial);
  segmax_combine<<<B * D / 256, 256, 0, stream>>>(partial, maxval);
  pool_gemm<<<dim3(B, 2), 256, 0, stream>>>(maxval, proj_w, proj_b, part, 0);

  for (int l = 0; l < 3; ++l) {
    agg_kernel<<<N / 4, 256, 0, stream>>>(xb, rowptr, csr, eps, l, hb);
    gemm_bias_leaky<<<dim3(D / LBN, N / LBM), 256, 0, stream>>>(
        hb, l1bt + (size_t)l * D * D, lin1_b + (size_t)l * D, tb, nullptr);
    gemm_bias_leaky<<<dim3(D / LBN, N / LBM), 256, 0, stream>>>(
        tb, l2bt + (size_t)l * D * D, lin2_b + (size_t)l * D, xb,
        (l == 2) ? xout : nullptr);
    segmax_partial<<<dim3(B, 8), 256, 0, stream>>>(xb, gstart, partial);
    segmax_combine<<<B * D / 256, 256, 0, stream>>>(partial, maxval);
    pool_gemm<<<dim3(B, 2), 256, 0, stream>>>(maxval, pool_w + (size_t)l * D * D,
                                              pool_b + (size_t)l * D, part, 1);
  }
}